// Round 15
// baseline (151.088 us; speedup 1.0000x reference)
//
#include <hip/hip_runtime.h>
#include <hip/hip_bf16.h>
#include <stdint.h>

// SequentialMLP: E=8, H=1024, F=1024, T=16384, Tpe=2048
#define T_TOK 16384
#define H_DIM 1024
#define F_DIM 1024
#define E_NUM 8
#define TPE   2048

typedef unsigned short u16;
typedef __attribute__((ext_vector_type(8))) short bf16x8;   // 8 bf16 (4 VGPRs)
typedef __attribute__((ext_vector_type(4))) float f32x4;    // MFMA accumulator
typedef __attribute__((ext_vector_type(8))) u16 u16x8;

__device__ __forceinline__ u16 f2bf(float x) {
  unsigned int u = __float_as_uint(x);
  u = (u + 0x7fffu + ((u >> 16) & 1u)) >> 16;   // RNE
  return (u16)u;
}

// async global->LDS, 16B per lane. LDS dest = wave-uniform base + lane*16.
#define GLD16(gp, lp)                                                          \
  __builtin_amdgcn_global_load_lds(                                            \
      (const __attribute__((address_space(1))) void*)(gp),                     \
      (__attribute__((address_space(3))) void*)(lp), 16, 0, 0)

#define VMW(N) asm volatile("s_waitcnt vmcnt(" #N ")" ::: "memory");

// ================================================================= prep pass
// r14/r9 prep (timed-best family). 64x64 tiles, tile[64][65]=16.6KB static
// LDS -> 8 blocks/CU for both roles.
// Blocks: [0,4096) x-cvt | [4096,8192) W1 tiles | [8192,10240) W2 tiles.
__global__ __launch_bounds__(256) void prep_all(
    const float* __restrict__ x, const float* __restrict__ W1,
    const float* __restrict__ W2, u16* __restrict__ xbf,
    u16* __restrict__ w1t, u16* __restrict__ w2t) {
  __shared__ float tile[64][65];
  const int bid = blockIdx.x;
  const int t = threadIdx.x;

  if (bid < 4096) {
    size_t base = (size_t)bid * 4096 + (size_t)t * 16;
    const float4* s = (const float4*)(x + base);
    float4 v0 = s[0], v1 = s[1], v2 = s[2], v3 = s[3];
    u16x8 o0, o1;
    o0[0] = f2bf(v0.x); o0[1] = f2bf(v0.y); o0[2] = f2bf(v0.z); o0[3] = f2bf(v0.w);
    o0[4] = f2bf(v1.x); o0[5] = f2bf(v1.y); o0[6] = f2bf(v1.z); o0[7] = f2bf(v1.w);
    o1[0] = f2bf(v2.x); o1[1] = f2bf(v2.y); o1[2] = f2bf(v2.z); o1[3] = f2bf(v2.w);
    o1[4] = f2bf(v3.x); o1[5] = f2bf(v3.y); o1[6] = f2bf(v3.z); o1[7] = f2bf(v3.w);
    *(u16x8*)(xbf + base) = o0;
    *(u16x8*)(xbf + base + 8) = o1;
    return;
  }

  const float* src; u16* dst; int R, C, e, rt, ct;
  if (bid < 8192) {
    int id = bid - 4096;
    e = id >> 9; int r2 = id & 511; rt = r2 >> 5; ct = r2 & 31;
    src = W1; dst = w1t; R = H_DIM; C = 2 * F_DIM;
  } else {
    int id = bid - 8192;
    e = id >> 8; int r2 = id & 255; rt = r2 >> 4; ct = r2 & 15;
    src = W2; dst = w2t; R = F_DIM; C = H_DIM;
  }
  const float* s = src + (size_t)e * R * C + (size_t)(rt << 6) * C + (ct << 6);
  int lr = t >> 4, lc = (t & 15) << 2;
#pragma unroll
  for (int i = 0; i < 4; i++) {
    float4 v = *(const float4*)(s + (size_t)(lr + i * 16) * C + lc);
    tile[lr + i * 16][lc + 0] = v.x;
    tile[lr + i * 16][lc + 1] = v.y;
    tile[lr + i * 16][lc + 2] = v.z;
    tile[lr + i * 16][lc + 3] = v.w;
  }
  __syncthreads();
  u16* d = dst + (size_t)e * C * R + (size_t)(ct << 6) * R + (rt << 6);
  int orow = t >> 2, ok = (t & 3) << 4;
  u16x8 o0, o1;
#pragma unroll
  for (int i = 0; i < 8; i++) o0[i] = f2bf(tile[ok + i][orow]);
#pragma unroll
  for (int i = 0; i < 8; i++) o1[i] = f2bf(tile[ok + 8 + i][orow]);
  *(u16x8*)(d + (size_t)orow * R + ok) = o0;
  *(u16x8*)(d + (size_t)orow * R + ok + 8) = o1;
}

// ====================================================== 256x256 GEMM, 16 waves
// r11 structure (best measured; GEMM schedule family closed) + ROUND-15:
// epilogue operands (probs/b1/b2, 2KB) staged into spare LDS at kernel start
// by waves 0/1, as the OLDEST vmcnt-queue entries (prologue vmcnt(2) retires
// them; in-loop counts unaffected). Removes the tail-latency global-load
// burst after the K-drain that the asm "memory" clobbers pin in place.
// Ledger: prologue B0(2) A0(2) B1(2) -> vmcnt(2), barrier;
// loop p0: A1q0  p1: A1q1  p3: B0'(2)+vmcnt(2)  p4: A0'q0  p5: A0'q1
// p7: B1'(2)+vmcnt(2). Swizzle byte ^= ((row&7)<<4) via inverse-swizzled
// global source (linear LDS dest, rule 21) + swizzled ds_read offset.

#define DSA2(b, h, ks)                                                         \
  _Pragma("unroll") for (int m2_ = 0; m2_ < 2; ++m2_)                          \
      aF[m2_] = *(const bf16x8*)(sm + (b) * 32768 + aRowBase +                 \
                                 ((h) * 2 + m2_) * 2048 + koff[ks]);

#define DSB4(b, ks)                                                            \
  _Pragma("unroll") for (int n_ = 0; n_ < 4; ++n_)                             \
      bF[n_] = *(const bf16x8*)(sm + 65536 + (b) * 32768 + bRowBase +          \
                                n_ * 2048 + koff[ks]);

#define MFMAP(h)                                                               \
  _Pragma("unroll") for (int n_ = 0; n_ < 4; ++n_)                             \
  _Pragma("unroll") for (int m2_ = 0; m2_ < 2; ++m2_)                          \
      acc[(h) * 2 + m2_][n_] = __builtin_amdgcn_mfma_f32_16x16x32_bf16(        \
          aF[m2_], bF[n_], acc[(h) * 2 + m2_][n_], 0, 0, 0);

#define PF_A(db, q, d) GLD16(aP[q] + (d), sm + (db) * 32768 + (q) * 16384 + tid * 16)
#define PF_B(db, q, d) GLD16(bP[q] + (d), sm + 65536 + (db) * 32768 + (q) * 16384 + tid * 16)

#define PHASEK(b, ks, h, PFC, WTC)                                             \
  do {                                                                         \
    DSA2(b, h, ks);                                                            \
    if ((h) == 0) { DSB4(b, ks); }                                             \
    PFC                                                                        \
    __builtin_amdgcn_s_setprio(1);                                             \
    MFMAP(h);                                                                  \
    __builtin_amdgcn_s_setprio(0);                                             \
    WTC                                                                        \
    __builtin_amdgcn_s_barrier();                                              \
  } while (0)

#define KLOOP_BODY                                                             \
  PF_B(0, 0, 0); PF_B(0, 1, 0);                                                \
  PF_A(0, 0, 0); PF_A(0, 1, 0);                                                \
  PF_B(1, 0, 64); PF_B(1, 1, 64);                                              \
  VMW(2)                                                                       \
  __builtin_amdgcn_s_barrier();                                                \
  for (int it = 0; it < 7; ++it) {                                             \
    PHASEK(0, 0, 0, PF_A(1, 0, 64);, );                                        \
    PHASEK(0, 0, 1, PF_A(1, 1, 64);, );                                        \
    PHASEK(0, 1, 0, , );                                                       \
    PHASEK(0, 1, 1, PF_B(0, 0, 128); PF_B(0, 1, 128);, VMW(2));                \
    PHASEK(1, 0, 0, PF_A(0, 0, 128);, );                                       \
    PHASEK(1, 0, 1, PF_A(0, 1, 128);, );                                       \
    PHASEK(1, 1, 0, , );                                                       \
    PHASEK(1, 1, 1, PF_B(1, 0, 192); PF_B(1, 1, 192);, VMW(2));                \
    _Pragma("unroll") for (int q_ = 0; q_ < 2; ++q_) {                         \
      aP[q_] += 128; bP[q_] += 128;                                            \
    }                                                                          \
  }                                                                            \
  PHASEK(0, 0, 0, PF_A(1, 0, 64);, );                                          \
  PHASEK(0, 0, 1, PF_A(1, 1, 64);, );                                          \
  PHASEK(0, 1, 0, , );                                                         \
  PHASEK(0, 1, 1, , VMW(0));                                                   \
  PHASEK(1, 0, 0, , );                                                         \
  PHASEK(1, 0, 1, , );                                                         \
  PHASEK(1, 1, 0, , );                                                         \
  PHASEK(1, 1, 1, , );

// ---------------------------------------------------------------- GEMM1+GLU
__global__ __launch_bounds__(1024) void gemm1_8p(
    const u16* __restrict__ xbf, const u16* __restrict__ w1t,
    const float* __restrict__ b1, const float* __restrict__ probs,
    u16* __restrict__ abf) {
  extern __shared__ char sm[];
  const int tid = threadIdx.x;
  const int lane = tid & 63;
  const int wid = tid >> 6;               // 0..15
  const int wm = wid >> 2, wn = wid & 3;  // 4x4 wave grid, wave tile 64x64
  const int bid = blockIdx.x;
  const int e = bid & 7;          // expert -> XCD pinning (round-robin bid%8)
  const int inner = bid >> 3;
  const int mt = inner >> 3, ct = inner & 7;
  const int tokBase = e * TPE + mt * 256;
  const int c0 = ct * 128;
  const int lrow = lane & 15, lkhi = lane >> 4;

  const u16* aP[2]; const u16* bP[2];
#pragma unroll
  for (int q = 0; q < 2; ++q) {
    int lin = q * 16384 + tid * 16;
    int lg = lin ^ (((lin >> 7) & 7) << 4);   // inverse swizzle (involution)
    int row = lg >> 7, kk = (lg & 127) >> 1;
    aP[q] = xbf + (size_t)(tokBase + row) * H_DIM + kk;
    // B row nn: alternate 32-blocks gate/lin so each wave owns matching pairs
    int col = (((row >> 5) & 1) << 10) + c0 + ((row >> 6) << 5) + (row & 31);
    bP[q] = w1t + (size_t)(e * 2 * F_DIM + col) * H_DIM + kk;
  }
  const int aRowBase = (wm * 64 + lrow) * 128;
  const int bRowBase = (wn * 64 + lrow) * 128;
  int koff[2];
#pragma unroll
  for (int ks = 0; ks < 2; ++ks)
    koff[ks] = ((ks << 6) | (lkhi << 4)) ^ ((lane & 7) << 4);

  f32x4 acc[4][4];
#pragma unroll
  for (int i = 0; i < 4; ++i)
#pragma unroll
    for (int j = 0; j < 4; ++j) acc[i][j] = f32x4{0.f, 0.f, 0.f, 0.f};
  bf16x8 aF[2], bF[4];

  // --- R15: stage epilogue operands into LDS [131072..133120) FIRST so they
  // are the oldest vmcnt entries (prologue vmcnt(2) retires them). ---
  if (wid == 0) {
    GLD16(probs + tokBase + lane * 4, sm + 131072);          // 1KB: 256 probs
  } else if (wid == 1) {
    const float* bsrc = (lane < 32)
        ? (b1 + e * 2 * F_DIM + c0 + lane * 4)               // gate bias 512B
        : (b1 + e * 2 * F_DIM + F_DIM + c0 + (lane - 32) * 4);  // lin 512B
    GLD16(bsrc, sm + 132096);
  }

  KLOOP_BODY

  // epilogue: a = silu(gate+b1g) * (lin+b1l+1) * p -> bf16 (operands from LDS)
#pragma unroll
  for (int j = 0; j < 2; ++j) {
    int cf = c0 + wn * 32 + j * 16 + lrow;
    int cofs = (wn * 32 + j * 16 + lrow) * 4;
    float gb = *(const float*)(sm + 132096 + cofs);
    float lb = *(const float*)(sm + 132608 + cofs);
#pragma unroll
    for (int i = 0; i < 4; ++i) {
      int tr0 = wm * 64 + i * 16 + lkhi * 4;
      int trow = tokBase + tr0;
#pragma unroll
      for (int r = 0; r < 4; ++r) {
        float g = acc[i][j][r] + gb;
        float l = acc[i][j + 2][r] + lb + 1.0f;
        float p = *(const float*)(sm + 131072 + (tr0 + r) * 4);
        float sig = 1.0f / (1.0f + __expf(-g));
        abf[(size_t)(trow + r) * F_DIM + cf] = f2bf(g * sig * l * p);
      }
    }
  }
}

// ---------------------------------------------------------------- GEMM2
__global__ __launch_bounds__(1024) void gemm2_8p(
    const u16* __restrict__ abf, const u16* __restrict__ w2t,
    const float* __restrict__ b2, float* __restrict__ out) {
  extern __shared__ char sm[];
  const int tid = threadIdx.x;
  const int lane = tid & 63;
  const int wid = tid >> 6;
  const int wm = wid >> 2, wn = wid & 3;
  const int bid = blockIdx.x;
  const int e = bid & 7;
  const int inner = bid >> 3;
  const int mt = inner >> 2, nt = inner & 3;
  const int tokBase = e * TPE + mt * 256;
  const int h0 = nt * 256;
  const int lrow = lane & 15, lkhi = lane >> 4;

  const u16* aP[2]; const u16* bP[2];
#pragma unroll
  for (int q = 0; q < 2; ++q) {
    int lin = q * 16384 + tid * 16;
    int lg = lin ^ (((lin >> 7) & 7) << 4);
    int row = lg >> 7, kk = (lg & 127) >> 1;
    aP[q] = abf + (size_t)(tokBase + row) * F_DIM + kk;
    bP[q] = w2t + (size_t)(e * H_DIM + h0 + row) * F_DIM + kk;
  }
  const int aRowBase = (wm * 64 + lrow) * 128;
  const int bRowBase = (wn * 64 + lrow) * 128;
  int koff[2];
#pragma unroll
  for (int ks = 0; ks < 2; ++ks)
    koff[ks] = ((ks << 6) | (lkhi << 4)) ^ ((lane & 7) << 4);

  f32x4 acc[4][4];
#pragma unroll
  for (int i = 0; i < 4; ++i)
#pragma unroll
    for (int j = 0; j < 4; ++j) acc[i][j] = f32x4{0.f, 0.f, 0.f, 0.f};
  bf16x8 aF[2], bF[4];

  // --- R15: stage b2 slice (1KB: 256 h-values) as oldest vmcnt entry ---
  if (wid == 0) {
    GLD16(b2 + e * H_DIM + h0 + lane * 4, sm + 131072);
  }

  KLOOP_BODY

#pragma unroll
  for (int j = 0; j < 4; ++j) {
    int h = h0 + wn * 64 + j * 16 + lrow;
    float bb = *(const float*)(sm + 131072 + (wn * 64 + j * 16 + lrow) * 4);
#pragma unroll
    for (int i = 0; i < 4; ++i) {
      int trow = tokBase + wm * 64 + i * 16 + lkhi * 4;
#pragma unroll
      for (int r = 0; r < 4; ++r)
        out[(size_t)(trow + r) * H_DIM + h] = acc[i][j][r] + bb;
    }
  }
}

// ---------------------------------------------------------------- launch
extern "C" void kernel_launch(void* const* d_in, const int* in_sizes, int n_in,
                              void* d_out, int out_size, void* d_ws,
                              size_t ws_size, hipStream_t stream) {
  const float* x     = (const float*)d_in[0];
  // d_in[1] tokens_per_expert: uniform (T/E) by construction, unused
  const float* probs = (const float*)d_in[2];
  const float* W1    = (const float*)d_in[3];
  const float* b1    = (const float*)d_in[4];
  const float* W2    = (const float*)d_in[5];
  const float* b2    = (const float*)d_in[6];
  float* out = (float*)d_out;

  // workspace: xbf[T,H] 32MB | w1t[E,2F,H] 32MB | w2t[E,H,F] 16MB | abf 32MB
  if (ws_size < 117440512u) return;
  char* ws = (char*)d_ws;
  u16* xbf = (u16*)(ws);
  u16* w1t = (u16*)(ws + 33554432);
  u16* w2t = (u16*)(ws + 67108864);
  u16* abf = (u16*)(ws + 83886080);

  (void)hipFuncSetAttribute(reinterpret_cast<const void*>(gemm1_8p),
                            hipFuncAttributeMaxDynamicSharedMemorySize, 133120);
  (void)hipFuncSetAttribute(reinterpret_cast<const void*>(gemm2_8p),
                            hipFuncAttributeMaxDynamicSharedMemorySize, 133120);

  prep_all<<<10240, 256, 0, stream>>>(x, W1, W2, xbf, w1t, w2t);
  gemm1_8p<<<E_NUM * 8 * 8, 1024, 133120, stream>>>(xbf, w1t, b1, probs, abf);
  gemm2_8p<<<E_NUM * 8 * 4, 1024, 133120, stream>>>(abf, w2t, b2, out);
}

// Round 17
// 149.438 us; speedup vs baseline: 1.0110x; 1.0110x over previous
//
#include <hip/hip_runtime.h>
#include <hip/hip_bf16.h>
#include <stdint.h>

// SequentialMLP: E=8, H=1024, F=1024, T=16384, Tpe=2048
#define T_TOK 16384
#define H_DIM 1024
#define F_DIM 1024
#define E_NUM 8
#define TPE   2048

// FINAL (r17 = r14, compile-fix of r16): best measured configuration.
//   prep_all: r9-family (64x64 tiles, 16.6KB LDS, 8 blocks/CU)   ~50us timed
//   gemm1_8p: 256x256/BK=64, 16 waves, counted-vmcnt, XOR-swz    ~70us (968TF)
//   gemm2_8p: same structure, 256x256 out tile                   ~28us

typedef unsigned short u16;
typedef __attribute__((ext_vector_type(8))) short bf16x8;   // 8 bf16 (4 VGPRs)
typedef __attribute__((ext_vector_type(4))) float f32x4;    // MFMA accumulator
typedef __attribute__((ext_vector_type(8))) u16 u16x8;

__device__ __forceinline__ u16 f2bf(float x) {
  unsigned int u = __float_as_uint(x);
  u = (u + 0x7fffu + ((u >> 16) & 1u)) >> 16;   // RNE
  return (u16)u;
}

// async global->LDS, 16B per lane. LDS dest = wave-uniform base + lane*16.
#define GLD16(gp, lp)                                                          \
  __builtin_amdgcn_global_load_lds(                                            \
      (const __attribute__((address_space(1))) void*)(gp),                     \
      (__attribute__((address_space(3))) void*)(lp), 16, 0, 0)

#define VMW(N) asm volatile("s_waitcnt vmcnt(" #N ")" ::: "memory");

// ================================================================= prep pass
// Blocks: [0,4096) x-cvt | [4096,8192) W1 tiles | [8192,10240) W2 tiles.
__global__ __launch_bounds__(256) void prep_all(
    const float* __restrict__ x, const float* __restrict__ W1,
    const float* __restrict__ W2, u16* __restrict__ xbf,
    u16* __restrict__ w1t, u16* __restrict__ w2t) {
  __shared__ float tile[64][65];
  const int bid = blockIdx.x;
  const int t = threadIdx.x;

  if (bid < 4096) {
    size_t base = (size_t)bid * 4096 + (size_t)t * 16;
    const float4* s = (const float4*)(x + base);
    float4 v0 = s[0], v1 = s[1], v2 = s[2], v3 = s[3];
    u16x8 o0, o1;
    o0[0] = f2bf(v0.x); o0[1] = f2bf(v0.y); o0[2] = f2bf(v0.z); o0[3] = f2bf(v0.w);
    o0[4] = f2bf(v1.x); o0[5] = f2bf(v1.y); o0[6] = f2bf(v1.z); o0[7] = f2bf(v1.w);
    o1[0] = f2bf(v2.x); o1[1] = f2bf(v2.y); o1[2] = f2bf(v2.z); o1[3] = f2bf(v2.w);
    o1[4] = f2bf(v3.x); o1[5] = f2bf(v3.y); o1[6] = f2bf(v3.z); o1[7] = f2bf(v3.w);
    *(u16x8*)(xbf + base) = o0;
    *(u16x8*)(xbf + base + 8) = o1;
    return;
  }

  const float* src; u16* dst; int R, C, e, rt, ct;
  if (bid < 8192) {
    int id = bid - 4096;
    e = id >> 9; int r2 = id & 511; rt = r2 >> 5; ct = r2 & 31;
    src = W1; dst = w1t; R = H_DIM; C = 2 * F_DIM;
  } else {
    int id = bid - 8192;
    e = id >> 8; int r2 = id & 255; rt = r2 >> 4; ct = r2 & 15;
    src = W2; dst = w2t; R = F_DIM; C = H_DIM;
  }
  const float* s = src + (size_t)e * R * C + (size_t)(rt << 6) * C + (ct << 6);
  int lr = t >> 4, lc = (t & 15) << 2;
#pragma unroll
  for (int i = 0; i < 4; i++) {
    float4 v = *(const float4*)(s + (size_t)(lr + i * 16) * C + lc);
    tile[lr + i * 16][lc + 0] = v.x;
    tile[lr + i * 16][lc + 1] = v.y;
    tile[lr + i * 16][lc + 2] = v.z;
    tile[lr + i * 16][lc + 3] = v.w;
  }
  __syncthreads();
  u16* d = dst + (size_t)e * C * R + (size_t)(ct << 6) * R + (rt << 6);
  int orow = t >> 2, ok = (t & 3) << 4;
  u16x8 o0, o1;
#pragma unroll
  for (int i = 0; i < 8; i++) o0[i] = f2bf(tile[ok + i][orow]);
#pragma unroll
  for (int i = 0; i < 8; i++) o1[i] = f2bf(tile[ok + 8 + i][orow]);
  *(u16x8*)(d + (size_t)orow * R + ok) = o0;
  *(u16x8*)(d + (size_t)orow * R + ok + 8) = o1;
}

// ====================================================== 256x256 GEMM, 16 waves
// BM=BN=256 / BK=64 / 128KB dbuf LDS, 1024 threads (16 waves, 4Mx4N).
// Ledger: prologue B0(2) A0(2) B1(2) -> vmcnt(2), barrier;
// loop p0: A1q0  p1: A1q1  p3: B0'(2)+vmcnt(2)  p4: A0'q0  p5: A0'q1
// p7: B1'(2)+vmcnt(2). Swizzle byte ^= ((row&7)<<4) via inverse-swizzled
// global source (linear LDS dest, rule 21) + swizzled ds_read offset.

#define DSA2(b, h, ks)                                                         \
  _Pragma("unroll") for (int m2_ = 0; m2_ < 2; ++m2_)                          \
      aF[m2_] = *(const bf16x8*)(sm + (b) * 32768 + aRowBase +                 \
                                 ((h) * 2 + m2_) * 2048 + koff[ks]);

#define DSB4(b, ks)                                                            \
  _Pragma("unroll") for (int n_ = 0; n_ < 4; ++n_)                             \
      bF[n_] = *(const bf16x8*)(sm + 65536 + (b) * 32768 + bRowBase +          \
                                n_ * 2048 + koff[ks]);

#define MFMAP(h)                                                               \
  _Pragma("unroll") for (int n_ = 0; n_ < 4; ++n_)                             \
  _Pragma("unroll") for (int m2_ = 0; m2_ < 2; ++m2_)                          \
      acc[(h) * 2 + m2_][n_] = __builtin_amdgcn_mfma_f32_16x16x32_bf16(        \
          aF[m2_], bF[n_], acc[(h) * 2 + m2_][n_], 0, 0, 0);

#define PF_A(db, q, d) GLD16(aP[q] + (d), sm + (db) * 32768 + (q) * 16384 + tid * 16)
#define PF_B(db, q, d) GLD16(bP[q] + (d), sm + 65536 + (db) * 32768 + (q) * 16384 + tid * 16)

#define PHASEK(b, ks, h, PFC, WTC)                                             \
  do {                                                                         \
    DSA2(b, h, ks);                                                            \
    if ((h) == 0) { DSB4(b, ks); }                                             \
    PFC                                                                        \
    __builtin_amdgcn_s_setprio(1);                                             \
    MFMAP(h);                                                                  \
    __builtin_amdgcn_s_setprio(0);                                             \
    WTC                                                                        \
    __builtin_amdgcn_s_barrier();                                              \
  } while (0)

#define KLOOP_BODY                                                             \
  PF_B(0, 0, 0); PF_B(0, 1, 0);                                                \
  PF_A(0, 0, 0); PF_A(0, 1, 0);                                                \
  PF_B(1, 0, 64); PF_B(1, 1, 64);                                              \
  VMW(2)                                                                       \
  __builtin_amdgcn_s_barrier();                                                \
  for (int it = 0; it < 7; ++it) {                                             \
    PHASEK(0, 0, 0, PF_A(1, 0, 64);, );                                        \
    PHASEK(0, 0, 1, PF_A(1, 1, 64);, );                                        \
    PHASEK(0, 1, 0, , );                                                       \
    PHASEK(0, 1, 1, PF_B(0, 0, 128); PF_B(0, 1, 128);, VMW(2));                \
    PHASEK(1, 0, 0, PF_A(0, 0, 128);, );                                       \
    PHASEK(1, 0, 1, PF_A(0, 1, 128);, );                                       \
    PHASEK(1, 1, 0, , );                                                       \
    PHASEK(1, 1, 1, PF_B(1, 0, 192); PF_B(1, 1, 192);, VMW(2));                \
    _Pragma("unroll") for (int q_ = 0; q_ < 2; ++q_) {                         \
      aP[q_] += 128; bP[q_] += 128;                                            \
    }                                                                          \
  }                                                                            \
  PHASEK(0, 0, 0, PF_A(1, 0, 64);, );                                          \
  PHASEK(0, 0, 1, PF_A(1, 1, 64);, );                                          \
  PHASEK(0, 1, 0, , );                                                         \
  PHASEK(0, 1, 1, , VMW(0));                                                   \
  PHASEK(1, 0, 0, , );                                                         \
  PHASEK(1, 0, 1, , );                                                         \
  PHASEK(1, 1, 0, , );                                                         \
  PHASEK(1, 1, 1, , );

// ---------------------------------------------------------------- GEMM1+GLU
__global__ __launch_bounds__(1024) void gemm1_8p(
    const u16* __restrict__ xbf, const u16* __restrict__ w1t,
    const float* __restrict__ b1, const float* __restrict__ probs,
    u16* __restrict__ abf) {
  extern __shared__ char sm[];
  const int tid = threadIdx.x;
  const int lane = tid & 63;
  const int wid = tid >> 6;               // 0..15
  const int wm = wid >> 2, wn = wid & 3;  // 4x4 wave grid, wave tile 64x64
  const int bid = blockIdx.x;
  const int e = bid & 7;          // expert -> XCD pinning (round-robin bid%8)
  const int inner = bid >> 3;
  const int mt = inner >> 3, ct = inner & 7;
  const int tokBase = e * TPE + mt * 256;
  const int c0 = ct * 128;
  const int lrow = lane & 15, lkhi = lane >> 4;

  const u16* aP[2]; const u16* bP[2];
#pragma unroll
  for (int q = 0; q < 2; ++q) {
    int lin = q * 16384 + tid * 16;
    int lg = lin ^ (((lin >> 7) & 7) << 4);   // inverse swizzle (involution)
    int row = lg >> 7, kk = (lg & 127) >> 1;
    aP[q] = xbf + (size_t)(tokBase + row) * H_DIM + kk;
    // B row nn: alternate 32-blocks gate/lin so each wave owns matching pairs
    int col = (((row >> 5) & 1) << 10) + c0 + ((row >> 6) << 5) + (row & 31);
    bP[q] = w1t + (size_t)(e * 2 * F_DIM + col) * H_DIM + kk;
  }
  const int aRowBase = (wm * 64 + lrow) * 128;
  const int bRowBase = (wn * 64 + lrow) * 128;
  int koff[2];
#pragma unroll
  for (int ks = 0; ks < 2; ++ks)
    koff[ks] = ((ks << 6) | (lkhi << 4)) ^ ((lane & 7) << 4);

  f32x4 acc[4][4];
#pragma unroll
  for (int i = 0; i < 4; ++i)
#pragma unroll
    for (int j = 0; j < 4; ++j) acc[i][j] = f32x4{0.f, 0.f, 0.f, 0.f};
  bf16x8 aF[2], bF[4];

  KLOOP_BODY

  // epilogue: a = silu(gate+b1g) * (lin+b1l+1) * p -> bf16
#pragma unroll
  for (int j = 0; j < 2; ++j) {
    int cf = c0 + wn * 32 + j * 16 + lrow;
    float gb = b1[e * 2 * F_DIM + cf];
    float lb = b1[e * 2 * F_DIM + F_DIM + cf];
#pragma unroll
    for (int i = 0; i < 4; ++i) {
      int trow = tokBase + wm * 64 + i * 16 + lkhi * 4;
#pragma unroll
      for (int r = 0; r < 4; ++r) {
        float g = acc[i][j][r] + gb;
        float l = acc[i][j + 2][r] + lb + 1.0f;
        float p = probs[trow + r];
        float sig = 1.0f / (1.0f + __expf(-g));
        abf[(size_t)(trow + r) * F_DIM + cf] = f2bf(g * sig * l * p);
      }
    }
  }
}

// ---------------------------------------------------------------- GEMM2
__global__ __launch_bounds__(1024) void gemm2_8p(
    const u16* __restrict__ abf, const u16* __restrict__ w2t,
    const float* __restrict__ b2, float* __restrict__ out) {
  extern __shared__ char sm[];
  const int tid = threadIdx.x;
  const int lane = tid & 63;
  const int wid = tid >> 6;
  const int wm = wid >> 2, wn = wid & 3;
  const int bid = blockIdx.x;
  const int e = bid & 7;
  const int inner = bid >> 3;
  const int mt = inner >> 2, nt = inner & 3;
  const int tokBase = e * TPE + mt * 256;
  const int h0 = nt * 256;
  const int lrow = lane & 15, lkhi = lane >> 4;

  const u16* aP[2]; const u16* bP[2];
#pragma unroll
  for (int q = 0; q < 2; ++q) {
    int lin = q * 16384 + tid * 16;
    int lg = lin ^ (((lin >> 7) & 7) << 4);
    int row = lg >> 7, kk = (lg & 127) >> 1;
    aP[q] = abf + (size_t)(tokBase + row) * F_DIM + kk;
    bP[q] = w2t + (size_t)(e * H_DIM + h0 + row) * F_DIM + kk;
  }
  const int aRowBase = (wm * 64 + lrow) * 128;
  const int bRowBase = (wn * 64 + lrow) * 128;
  int koff[2];
#pragma unroll
  for (int ks = 0; ks < 2; ++ks)
    koff[ks] = ((ks << 6) | (lkhi << 4)) ^ ((lane & 7) << 4);

  f32x4 acc[4][4];
#pragma unroll
  for (int i = 0; i < 4; ++i)
#pragma unroll
    for (int j = 0; j < 4; ++j) acc[i][j] = f32x4{0.f, 0.f, 0.f, 0.f};
  bf16x8 aF[2], bF[4];

  KLOOP_BODY

#pragma unroll
  for (int j = 0; j < 4; ++j) {
    int h = h0 + wn * 64 + j * 16 + lrow;
    float bb = b2[e * H_DIM + h];
#pragma unroll
    for (int i = 0; i < 4; ++i) {
      int trow = tokBase + wm * 64 + i * 16 + lkhi * 4;
#pragma unroll
      for (int r = 0; r < 4; ++r)
        out[(size_t)(trow + r) * H_DIM + h] = acc[i][j][r] + bb;
    }
  }
}

// ---------------------------------------------------------------- launch
extern "C" void kernel_launch(void* const* d_in, const int* in_sizes, int n_in,
                              void* d_out, int out_size, void* d_ws,
                              size_t ws_size, hipStream_t stream) {
  const float* x     = (const float*)d_in[0];
  // d_in[1] tokens_per_expert: uniform (T/E) by construction, unused
  const float* probs = (const float*)d_in[2];
  const float* W1    = (const float*)d_in[3];
  const float* b1    = (const float*)d_in[4];
  const float* W2    = (const float*)d_in[5];
  const float* b2    = (const float*)d_in[6];
  float* out = (float*)d_out;

  // workspace: xbf[T,H] 32MB | w1t[E,2F,H] 32MB | w2t[E,H,F] 16MB | abf 32MB
  if (ws_size < 117440512u) return;
  char* ws = (char*)d_ws;
  u16* xbf = (u16*)(ws);
  u16* w1t = (u16*)(ws + 33554432);
  u16* w2t = (u16*)(ws + 67108864);
  u16* abf = (u16*)(ws + 83886080);

  (void)hipFuncSetAttribute(reinterpret_cast<const void*>(gemm1_8p),
                            hipFuncAttributeMaxDynamicSharedMemorySize, 131072);
  (void)hipFuncSetAttribute(reinterpret_cast<const void*>(gemm2_8p),
                            hipFuncAttributeMaxDynamicSharedMemorySize, 131072);

  prep_all<<<10240, 256, 0, stream>>>(x, W1, W2, xbf, w1t, w2t);
  gemm1_8p<<<E_NUM * 8 * 8, 1024, 131072, stream>>>(xbf, w1t, b1, probs, abf);
  gemm2_8p<<<E_NUM * 8 * 4, 1024, 131072, stream>>>(abf, w2t, b2, out);
}

// Round 18
// 148.378 us; speedup vs baseline: 1.0183x; 1.0071x over previous
//
#include <hip/hip_runtime.h>
#include <hip/hip_bf16.h>
#include <stdint.h>

// SequentialMLP: E=8, H=1024, F=1024, T=16384, Tpe=2048
#define T_TOK 16384
#define H_DIM 1024
#define F_DIM 1024
#define E_NUM 8
#define TPE   2048

// FINAL (locked; = r14/r17, best measured across 17 rounds; 148.7-149.4us):
//   prep_all: 64x64 transpose tiles, 16.6KB LDS, 8 blocks/CU    ~50us timed
//   gemm1_8p: 256x256/BK=64, 16 waves, counted-vmcnt, XOR-swz   ~70us (~970TF)
//   gemm2_8p: same structure                                    ~28us
// Measured-dead-ends (do not revisit): per-phase barrier variants x6,
// barrier-free compute (r8), reg-staged A (r4, 2.4x worse), LDS-free
// transpose (r12, write-scatter), 33KB-LDS prep (r10/r13), epilogue-LDS
// staging (r15, +2.3us).

typedef unsigned short u16;
typedef __attribute__((ext_vector_type(8))) short bf16x8;   // 8 bf16 (4 VGPRs)
typedef __attribute__((ext_vector_type(4))) float f32x4;    // MFMA accumulator
typedef __attribute__((ext_vector_type(8))) u16 u16x8;

__device__ __forceinline__ u16 f2bf(float x) {
  unsigned int u = __float_as_uint(x);
  u = (u + 0x7fffu + ((u >> 16) & 1u)) >> 16;   // RNE
  return (u16)u;
}

// async global->LDS, 16B per lane. LDS dest = wave-uniform base + lane*16.
#define GLD16(gp, lp)                                                          \
  __builtin_amdgcn_global_load_lds(                                            \
      (const __attribute__((address_space(1))) void*)(gp),                     \
      (__attribute__((address_space(3))) void*)(lp), 16, 0, 0)

#define VMW(N) asm volatile("s_waitcnt vmcnt(" #N ")" ::: "memory");

// ================================================================= prep pass
// Blocks: [0,4096) x-cvt | [4096,8192) W1 tiles | [8192,10240) W2 tiles.
__global__ __launch_bounds__(256) void prep_all(
    const float* __restrict__ x, const float* __restrict__ W1,
    const float* __restrict__ W2, u16* __restrict__ xbf,
    u16* __restrict__ w1t, u16* __restrict__ w2t) {
  __shared__ float tile[64][65];
  const int bid = blockIdx.x;
  const int t = threadIdx.x;

  if (bid < 4096) {
    size_t base = (size_t)bid * 4096 + (size_t)t * 16;
    const float4* s = (const float4*)(x + base);
    float4 v0 = s[0], v1 = s[1], v2 = s[2], v3 = s[3];
    u16x8 o0, o1;
    o0[0] = f2bf(v0.x); o0[1] = f2bf(v0.y); o0[2] = f2bf(v0.z); o0[3] = f2bf(v0.w);
    o0[4] = f2bf(v1.x); o0[5] = f2bf(v1.y); o0[6] = f2bf(v1.z); o0[7] = f2bf(v1.w);
    o1[0] = f2bf(v2.x); o1[1] = f2bf(v2.y); o1[2] = f2bf(v2.z); o1[3] = f2bf(v2.w);
    o1[4] = f2bf(v3.x); o1[5] = f2bf(v3.y); o1[6] = f2bf(v3.z); o1[7] = f2bf(v3.w);
    *(u16x8*)(xbf + base) = o0;
    *(u16x8*)(xbf + base + 8) = o1;
    return;
  }

  const float* src; u16* dst; int R, C, e, rt, ct;
  if (bid < 8192) {
    int id = bid - 4096;
    e = id >> 9; int r2 = id & 511; rt = r2 >> 5; ct = r2 & 31;
    src = W1; dst = w1t; R = H_DIM; C = 2 * F_DIM;
  } else {
    int id = bid - 8192;
    e = id >> 8; int r2 = id & 255; rt = r2 >> 4; ct = r2 & 15;
    src = W2; dst = w2t; R = F_DIM; C = H_DIM;
  }
  const float* s = src + (size_t)e * R * C + (size_t)(rt << 6) * C + (ct << 6);
  int lr = t >> 4, lc = (t & 15) << 2;
#pragma unroll
  for (int i = 0; i < 4; i++) {
    float4 v = *(const float4*)(s + (size_t)(lr + i * 16) * C + lc);
    tile[lr + i * 16][lc + 0] = v.x;
    tile[lr + i * 16][lc + 1] = v.y;
    tile[lr + i * 16][lc + 2] = v.z;
    tile[lr + i * 16][lc + 3] = v.w;
  }
  __syncthreads();
  u16* d = dst + (size_t)e * C * R + (size_t)(ct << 6) * R + (rt << 6);
  int orow = t >> 2, ok = (t & 3) << 4;
  u16x8 o0, o1;
#pragma unroll
  for (int i = 0; i < 8; i++) o0[i] = f2bf(tile[ok + i][orow]);
#pragma unroll
  for (int i = 0; i < 8; i++) o1[i] = f2bf(tile[ok + 8 + i][orow]);
  *(u16x8*)(d + (size_t)orow * R + ok) = o0;
  *(u16x8*)(d + (size_t)orow * R + ok + 8) = o1;
}

// ====================================================== 256x256 GEMM, 16 waves
// BM=BN=256 / BK=64 / 128KB dbuf LDS, 1024 threads (16 waves, 4Mx4N).
// Ledger: prologue B0(2) A0(2) B1(2) -> vmcnt(2), barrier;
// loop p0: A1q0  p1: A1q1  p3: B0'(2)+vmcnt(2)  p4: A0'q0  p5: A0'q1
// p7: B1'(2)+vmcnt(2). Swizzle byte ^= ((row&7)<<4) via inverse-swizzled
// global source (linear LDS dest, rule 21) + swizzled ds_read offset.

#define DSA2(b, h, ks)                                                         \
  _Pragma("unroll") for (int m2_ = 0; m2_ < 2; ++m2_)                          \
      aF[m2_] = *(const bf16x8*)(sm + (b) * 32768 + aRowBase +                 \
                                 ((h) * 2 + m2_) * 2048 + koff[ks]);

#define DSB4(b, ks)                                                            \
  _Pragma("unroll") for (int n_ = 0; n_ < 4; ++n_)                             \
      bF[n_] = *(const bf16x8*)(sm + 65536 + (b) * 32768 + bRowBase +          \
                                n_ * 2048 + koff[ks]);

#define MFMAP(h)                                                               \
  _Pragma("unroll") for (int n_ = 0; n_ < 4; ++n_)                             \
  _Pragma("unroll") for (int m2_ = 0; m2_ < 2; ++m2_)                          \
      acc[(h) * 2 + m2_][n_] = __builtin_amdgcn_mfma_f32_16x16x32_bf16(        \
          aF[m2_], bF[n_], acc[(h) * 2 + m2_][n_], 0, 0, 0);

#define PF_A(db, q, d) GLD16(aP[q] + (d), sm + (db) * 32768 + (q) * 16384 + tid * 16)
#define PF_B(db, q, d) GLD16(bP[q] + (d), sm + 65536 + (db) * 32768 + (q) * 16384 + tid * 16)

#define PHASEK(b, ks, h, PFC, WTC)                                             \
  do {                                                                         \
    DSA2(b, h, ks);                                                            \
    if ((h) == 0) { DSB4(b, ks); }                                             \
    PFC                                                                        \
    __builtin_amdgcn_s_setprio(1);                                             \
    MFMAP(h);                                                                  \
    __builtin_amdgcn_s_setprio(0);                                             \
    WTC                                                                        \
    __builtin_amdgcn_s_barrier();                                              \
  } while (0)

#define KLOOP_BODY                                                             \
  PF_B(0, 0, 0); PF_B(0, 1, 0);                                                \
  PF_A(0, 0, 0); PF_A(0, 1, 0);                                                \
  PF_B(1, 0, 64); PF_B(1, 1, 64);                                              \
  VMW(2)                                                                       \
  __builtin_amdgcn_s_barrier();                                                \
  for (int it = 0; it < 7; ++it) {                                             \
    PHASEK(0, 0, 0, PF_A(1, 0, 64);, );                                        \
    PHASEK(0, 0, 1, PF_A(1, 1, 64);, );                                        \
    PHASEK(0, 1, 0, , );                                                       \
    PHASEK(0, 1, 1, PF_B(0, 0, 128); PF_B(0, 1, 128);, VMW(2));                \
    PHASEK(1, 0, 0, PF_A(0, 0, 128);, );                                       \
    PHASEK(1, 0, 1, PF_A(0, 1, 128);, );                                       \
    PHASEK(1, 1, 0, , );                                                       \
    PHASEK(1, 1, 1, PF_B(1, 0, 192); PF_B(1, 1, 192);, VMW(2));                \
    _Pragma("unroll") for (int q_ = 0; q_ < 2; ++q_) {                         \
      aP[q_] += 128; bP[q_] += 128;                                            \
    }                                                                          \
  }                                                                            \
  PHASEK(0, 0, 0, PF_A(1, 0, 64);, );                                          \
  PHASEK(0, 0, 1, PF_A(1, 1, 64);, );                                          \
  PHASEK(0, 1, 0, , );                                                         \
  PHASEK(0, 1, 1, , VMW(0));                                                   \
  PHASEK(1, 0, 0, , );                                                         \
  PHASEK(1, 0, 1, , );                                                         \
  PHASEK(1, 1, 0, , );                                                         \
  PHASEK(1, 1, 1, , );

// ---------------------------------------------------------------- GEMM1+GLU
__global__ __launch_bounds__(1024) void gemm1_8p(
    const u16* __restrict__ xbf, const u16* __restrict__ w1t,
    const float* __restrict__ b1, const float* __restrict__ probs,
    u16* __restrict__ abf) {
  extern __shared__ char sm[];
  const int tid = threadIdx.x;
  const int lane = tid & 63;
  const int wid = tid >> 6;               // 0..15
  const int wm = wid >> 2, wn = wid & 3;  // 4x4 wave grid, wave tile 64x64
  const int bid = blockIdx.x;
  const int e = bid & 7;          // expert -> XCD pinning (round-robin bid%8)
  const int inner = bid >> 3;
  const int mt = inner >> 3, ct = inner & 7;
  const int tokBase = e * TPE + mt * 256;
  const int c0 = ct * 128;
  const int lrow = lane & 15, lkhi = lane >> 4;

  const u16* aP[2]; const u16* bP[2];
#pragma unroll
  for (int q = 0; q < 2; ++q) {
    int lin = q * 16384 + tid * 16;
    int lg = lin ^ (((lin >> 7) & 7) << 4);   // inverse swizzle (involution)
    int row = lg >> 7, kk = (lg & 127) >> 1;
    aP[q] = xbf + (size_t)(tokBase + row) * H_DIM + kk;
    // B row nn: alternate 32-blocks gate/lin so each wave owns matching pairs
    int col = (((row >> 5) & 1) << 10) + c0 + ((row >> 6) << 5) + (row & 31);
    bP[q] = w1t + (size_t)(e * 2 * F_DIM + col) * H_DIM + kk;
  }
  const int aRowBase = (wm * 64 + lrow) * 128;
  const int bRowBase = (wn * 64 + lrow) * 128;
  int koff[2];
#pragma unroll
  for (int ks = 0; ks < 2; ++ks)
    koff[ks] = ((ks << 6) | (lkhi << 4)) ^ ((lane & 7) << 4);

  f32x4 acc[4][4];
#pragma unroll
  for (int i = 0; i < 4; ++i)
#pragma unroll
    for (int j = 0; j < 4; ++j) acc[i][j] = f32x4{0.f, 0.f, 0.f, 0.f};
  bf16x8 aF[2], bF[4];

  KLOOP_BODY

  // epilogue: a = silu(gate+b1g) * (lin+b1l+1) * p -> bf16
#pragma unroll
  for (int j = 0; j < 2; ++j) {
    int cf = c0 + wn * 32 + j * 16 + lrow;
    float gb = b1[e * 2 * F_DIM + cf];
    float lb = b1[e * 2 * F_DIM + F_DIM + cf];
#pragma unroll
    for (int i = 0; i < 4; ++i) {
      int trow = tokBase + wm * 64 + i * 16 + lkhi * 4;
#pragma unroll
      for (int r = 0; r < 4; ++r) {
        float g = acc[i][j][r] + gb;
        float l = acc[i][j + 2][r] + lb + 1.0f;
        float p = probs[trow + r];
        float sig = 1.0f / (1.0f + __expf(-g));
        abf[(size_t)(trow + r) * F_DIM + cf] = f2bf(g * sig * l * p);
      }
    }
  }
}

// ---------------------------------------------------------------- GEMM2
__global__ __launch_bounds__(1024) void gemm2_8p(
    const u16* __restrict__ abf, const u16* __restrict__ w2t,
    const float* __restrict__ b2, float* __restrict__ out) {
  extern __shared__ char sm[];
  const int tid = threadIdx.x;
  const int lane = tid & 63;
  const int wid = tid >> 6;
  const int wm = wid >> 2, wn = wid & 3;
  const int bid = blockIdx.x;
  const int e = bid & 7;
  const int inner = bid >> 3;
  const int mt = inner >> 2, nt = inner & 3;
  const int tokBase = e * TPE + mt * 256;
  const int h0 = nt * 256;
  const int lrow = lane & 15, lkhi = lane >> 4;

  const u16* aP[2]; const u16* bP[2];
#pragma unroll
  for (int q = 0; q < 2; ++q) {
    int lin = q * 16384 + tid * 16;
    int lg = lin ^ (((lin >> 7) & 7) << 4);
    int row = lg >> 7, kk = (lg & 127) >> 1;
    aP[q] = abf + (size_t)(tokBase + row) * F_DIM + kk;
    bP[q] = w2t + (size_t)(e * H_DIM + h0 + row) * F_DIM + kk;
  }
  const int aRowBase = (wm * 64 + lrow) * 128;
  const int bRowBase = (wn * 64 + lrow) * 128;
  int koff[2];
#pragma unroll
  for (int ks = 0; ks < 2; ++ks)
    koff[ks] = ((ks << 6) | (lkhi << 4)) ^ ((lane & 7) << 4);

  f32x4 acc[4][4];
#pragma unroll
  for (int i = 0; i < 4; ++i)
#pragma unroll
    for (int j = 0; j < 4; ++j) acc[i][j] = f32x4{0.f, 0.f, 0.f, 0.f};
  bf16x8 aF[2], bF[4];

  KLOOP_BODY

#pragma unroll
  for (int j = 0; j < 4; ++j) {
    int h = h0 + wn * 64 + j * 16 + lrow;
    float bb = b2[e * H_DIM + h];
#pragma unroll
    for (int i = 0; i < 4; ++i) {
      int trow = tokBase + wm * 64 + i * 16 + lkhi * 4;
#pragma unroll
      for (int r = 0; r < 4; ++r)
        out[(size_t)(trow + r) * H_DIM + h] = acc[i][j][r] + bb;
    }
  }
}

// ---------------------------------------------------------------- launch
extern "C" void kernel_launch(void* const* d_in, const int* in_sizes, int n_in,
                              void* d_out, int out_size, void* d_ws,
                              size_t ws_size, hipStream_t stream) {
  const float* x     = (const float*)d_in[0];
  // d_in[1] tokens_per_expert: uniform (T/E) by construction, unused
  const float* probs = (const float*)d_in[2];
  const float* W1    = (const float*)d_in[3];
  const float* b1    = (const float*)d_in[4];
  const float* W2    = (const float*)d_in[5];
  const float* b2    = (const float*)d_in[6];
  float* out = (float*)d_out;

  // workspace: xbf[T,H] 32MB | w1t[E,2F,H] 32MB | w2t[E,H,F] 16MB | abf 32MB
  if (ws_size < 117440512u) return;
  char* ws = (char*)d_ws;
  u16* xbf = (u16*)(ws);
  u16* w1t = (u16*)(ws + 33554432);
  u16* w2t = (u16*)(ws + 67108864);
  u16* abf = (u16*)(ws + 83886080);

  (void)hipFuncSetAttribute(reinterpret_cast<const void*>(gemm1_8p),
                            hipFuncAttributeMaxDynamicSharedMemorySize, 131072);
  (void)hipFuncSetAttribute(reinterpret_cast<const void*>(gemm2_8p),
                            hipFuncAttributeMaxDynamicSharedMemorySize, 131072);

  prep_all<<<10240, 256, 0, stream>>>(x, W1, W2, xbf, w1t, w2t);
  gemm1_8p<<<E_NUM * 8 * 8, 1024, 131072, stream>>>(xbf, w1t, b1, probs, abf);
  gemm2_8p<<<E_NUM * 8 * 4, 1024, 131072, stream>>>(abf, w2t, b2, out);
}